// Round 5
// baseline (275.275 us; speedup 1.0000x reference)
//
#include <hip/hip_runtime.h>

// Static problem config (from reference):
//   HEIGHT=WIDTH=64, NUM_FRAMES=16, DIM=1280
//   GRIDS: (8,32,32) (16,16,16) (4,48,48) (1,64,64)
//   token offsets: 0, 8192, 12288, 21504, total 25600
//
// FULLY FUSED, occupancy-tuned: one kernel, 32-channel d-tiles.
// Each block owns (one output row of one sample, one 32-ch d-tile):
// separable bicubic resize of that row into LDS, then stream
// out = x + pe + tw over all t frames.  LDS ~17.9 KB -> 8 blocks/CU.
//
// Row map (160 rows x 40 d-tiles = 6400 blocks):
//   rows  0..31  sample 0: 32x32, t=8,  tok_off 0,     hw 1024
//   rows 32..47  sample 1: 16x16, t=16, tok_off 8192,  hw 256
//   rows 48..95  sample 2: 48x48, t=4,  tok_off 12288, hw 2304
//   rows 96..159 sample 3: 64x64, t=1,  tok_off 21504  (pe = weight, no tw)

__device__ __forceinline__ float keys_cubic(float x) {
    x = fabsf(x);
    if (x >= 2.0f) return 0.0f;
    if (x >= 1.0f) return ((-0.5f * x + 2.5f) * x - 4.0f) * x + 2.0f;
    return ((1.5f * x - 2.5f) * x) * x + 1.0f;
}

// jax.image.resize 'bicubic', antialias=True, downsample 64 -> out_size.
__device__ __forceinline__ void tap_params(int o, int out_size,
                                           int& i0, int& n, float& sf,
                                           float& inv_ks, float& inv_sum) {
    float inv_scale = 64.0f / (float)out_size;   // > 1 for all our cases
    float ks = inv_scale;                        // kernel_scale = max(inv_scale,1)
    float radius = 2.0f * ks;
    sf = ((float)o + 0.5f) * inv_scale - 0.5f;
    int lo = (int)ceilf(sf - radius); if (lo < 0) lo = 0;
    int hi = (int)floorf(sf + radius); if (hi > 63) hi = 63;
    n = hi - lo + 1;
    i0 = lo;
    inv_ks = 1.0f / ks;
    float sum = 0.0f;
    for (int k = 0; k < n; ++k)
        sum += keys_cubic((sf - (float)(lo + k)) * inv_ks);
    inv_sum = 1.0f / sum;
}

#define NDT 40            // d-tiles of 32 channels
#define TMP_STRIDE 36     // 32 floats + 4 pad (bank spread)
#define PE_STRIDE  36
#define MAXTAP 17         // out=16 -> radius 8 -> up to 17 taps

__global__ __launch_bounds__(256, 8) void fused_pe_kernel(const float* __restrict__ x,
                                                          const float* __restrict__ weight,
                                                          const float* __restrict__ tw,
                                                          float* __restrict__ out) {
    __shared__ float tmp[64 * TMP_STRIDE];     // H-resized row: [src col][32 ch]  9216 B
    __shared__ float pe_lds[48 * PE_STRIDE];   // final pe row:  [out col][32 ch]  6912 B
    __shared__ float vcoef[MAXTAP];            // vertical taps (1/sum folded)
    __shared__ int   vmeta[2];                 // i0, n
    __shared__ float hcoef[336];               // per-column taps, stride hs       1344 B
    __shared__ int   hj0[48];
    __shared__ int   hn[48];

    int td  = blockIdx.x % NDT;
    int row = blockIdx.x / NDT;
    int d0  = td * 32;
    int tid = threadIdx.x;

    if (row >= 96) {
        // ---- sample 3: identity pe (weight row), single frame, no tw ----
        int oy = row - 96;
        const float* wrow = weight + (size_t)oy * 64 * 1280 + d0;
        size_t obase = (size_t)(21504 + oy * 64) * 1280 + d0;
        for (int item = tid; item < 512; item += 256) {   // 64 cols x 8 f4
            int ox = item >> 3, f4 = item & 7;
            size_t xo = obase + (size_t)ox * 1280 + (f4 << 2);
            float4 xv = *(const float4*)(x + xo);
            float4 pv = *(const float4*)(wrow + (size_t)ox * 1280 + (f4 << 2));
            float4 o = make_float4(xv.x + pv.x, xv.y + pv.y, xv.z + pv.z, xv.w + pv.w);
            *(float4*)(out + xo) = o;
        }
    } else {
        // ---- resize samples ----
        int out_h, out_w, oy, t, tok_off, hw, hs;
        if (row < 32)      { out_h = 32; out_w = 32; oy = row;      t = 8;  tok_off = 0;     hw = 1024; hs = 10; }
        else if (row < 48) { out_h = 16; out_w = 16; oy = row - 32; t = 16; tok_off = 8192;  hw = 256;  hs = 18; }
        else               { out_h = 48; out_w = 48; oy = row - 48; t = 4;  tok_off = 12288; hw = 2304; hs = 7;  }

        // Tap tables (1/sum folded in). Vertical: one thread in wave 3;
        // horizontal: one thread per output column (all in wave 0).
        if (tid == 192) {
            int i0, n; float sf, ik, is;
            tap_params(oy, out_h, i0, n, sf, ik, is);
            vmeta[0] = i0; vmeta[1] = n;
            for (int k = 0; k < n; ++k)
                vcoef[k] = keys_cubic((sf - (float)(i0 + k)) * ik) * is;
        }
        if (tid < out_w) {
            int j0, n; float sf, ik, is;
            tap_params(tid, out_w, j0, n, sf, ik, is);
            hj0[tid] = j0; hn[tid] = n;
            for (int k = 0; k < n; ++k)
                hcoef[tid * hs + k] = keys_cubic((sf - (float)(j0 + k)) * ik) * is;
        }
        __syncthreads();

        // Stage 1: vertical (H) resize of this output row into tmp.
        // 64 src cols x 8 f4 = 512 items -> 2 iterations.
        int i0 = vmeta[0], nh = vmeta[1];
        for (int item = tid; item < 512; item += 256) {
            int sx = item >> 3;
            int f4 = item & 7;
            const float* src = weight + (size_t)sx * 1280 + d0 + (f4 << 2);
            float4 acc = make_float4(0.f, 0.f, 0.f, 0.f);
            for (int k = 0; k < nh; ++k) {
                float c = vcoef[k];    // broadcast, conflict-free
                float4 v = *(const float4*)(src + (size_t)(i0 + k) * (64 * 1280));
                acc.x += c * v.x; acc.y += c * v.y; acc.z += c * v.z; acc.w += c * v.w;
            }
            *(float4*)&tmp[sx * TMP_STRIDE + (f4 << 2)] = acc;
        }
        __syncthreads();

        // Stage 2: horizontal (W) resize from tmp into pe_lds.
        int nitems = out_w << 3;               // 128 / 256 / 384
        for (int item = tid; item < nitems; item += 256) {
            int ox = item >> 3;
            int f4 = item & 7;
            int j0 = hj0[ox], nw = hn[ox];
            const float* hc = &hcoef[ox * hs];
            float4 acc = make_float4(0.f, 0.f, 0.f, 0.f);
            for (int k = 0; k < nw; ++k) {
                float c = hc[k];
                float4 v = *(const float4*)&tmp[(j0 + k) * TMP_STRIDE + (f4 << 2)];
                acc.x += c * v.x; acc.y += c * v.y; acc.z += c * v.z; acc.w += c * v.w;
            }
            *(float4*)&pe_lds[ox * PE_STRIDE + (f4 << 2)] = acc;
        }
        __syncthreads();

        // Stage 3: stream out = x + pe + tw, collapsed over (frame x item)
        // so every thread stays busy even when nitems < 256 (16x16 sample).
        // Increment-correct indexing: nitems >= 128, so at most 2 wraps/step.
        size_t rbase = (size_t)(tok_off + oy * out_w) * 1280 + d0;
        int f = 0, it = tid;
        if (it >= nitems) { it -= nitems; f = 1; }     // tid < 256 <= 2*nitems
        while (f < t) {
            int ox = it >> 3, f4 = it & 7;
            size_t xo = rbase + (size_t)f * hw * 1280 + (size_t)ox * 1280 + (f4 << 2);
            float4 xv = *(const float4*)(x + xo);
            float4 pv = *(const float4*)&pe_lds[ox * PE_STRIDE + (f4 << 2)];
            float4 tv = *(const float4*)(tw + (size_t)f * 1280 + d0 + (f4 << 2));
            float4 o = make_float4(xv.x + pv.x + tv.x, xv.y + pv.y + tv.y,
                                   xv.z + pv.z + tv.z, xv.w + pv.w + tv.w);
            *(float4*)(out + xo) = o;
            it += 256;
            if (it >= nitems) { it -= nitems; ++f; }
            if (it >= nitems) { it -= nitems; ++f; }
        }
    }
}

extern "C" void kernel_launch(void* const* d_in, const int* in_sizes, int n_in,
                              void* d_out, int out_size, void* d_ws, size_t ws_size,
                              hipStream_t stream) {
    const float* x      = (const float*)d_in[0];   // [25600,1280]
    const float* weight = (const float*)d_in[1];   // [64,64,1280]
    const float* tw     = (const float*)d_in[2];   // [16,1280]
    // d_in[3] = grid_thws (static metadata, hard-coded)
    float* out = (float*)d_out;

    hipLaunchKernelGGL(fused_pe_kernel, dim3(160 * NDT), dim3(256), 0, stream,
                       x, weight, tw, out);
}

// Round 6
// 254.590 us; speedup vs baseline: 1.0812x; 1.0812x over previous
//
#include <hip/hip_runtime.h>

// Static problem config (from reference):
//   HEIGHT=WIDTH=64, NUM_FRAMES=16, DIM=1280
//   GRIDS: (8,32,32) (16,16,16) (4,48,48) (1,64,64)
//   token offsets: 0, 8192, 12288, 21504, total 25600
//
// Two kernels, decoupled (fused variant measured slower: resize phase +
// LDS-coupled streaming capped BW at 2.2-2.5 TB/s):
//   1) resize2d_kernel: separable bicubic weight[64][64][D] -> pe{32,16,48} in ws
//   2) add_pe_kernel:   wave-per-token streaming out = x + pe (+ tw)
//
// ws layout (float elements):
//   pe32 [32*32][1280] @ 0         (1,310,720)
//   pe16 [16*16][1280] @ 1,310,720 (  327,680)
//   pe48 [48*48][1280] @ 1,638,400 (2,949,120)

#define PE32_OFF 0
#define PE16_OFF 1310720
#define PE48_OFF 1638400

typedef float f32x4 __attribute__((ext_vector_type(4)));

__device__ __forceinline__ float keys_cubic(float x) {
    x = fabsf(x);
    if (x >= 2.0f) return 0.0f;
    if (x >= 1.0f) return ((-0.5f * x + 2.5f) * x - 4.0f) * x + 2.0f;
    return ((1.5f * x - 2.5f) * x) * x + 1.0f;
}

// jax.image.resize 'bicubic', antialias=True, downsample 64 -> out_size.
__device__ __forceinline__ void tap_params(int o, int out_size,
                                           int& i0, int& n, float& sf,
                                           float& inv_ks, float& inv_sum) {
    float inv_scale = 64.0f / (float)out_size;   // > 1 for all our cases
    float ks = inv_scale;                        // kernel_scale = max(inv_scale,1)
    float radius = 2.0f * ks;
    sf = ((float)o + 0.5f) * inv_scale - 0.5f;
    int lo = (int)ceilf(sf - radius); if (lo < 0) lo = 0;
    int hi = (int)floorf(sf + radius); if (hi > 63) hi = 63;
    n = hi - lo + 1;
    i0 = lo;
    inv_ks = 1.0f / ks;
    float sum = 0.0f;
    for (int k = 0; k < n; ++k)
        sum += keys_cubic((sf - (float)(lo + k)) * inv_ks);
    inv_sum = 1.0f / sum;
}

// Fused separable bicubic resize (round-1 version, proven).
// One block per (output row, 64-ch d-tile); grid 96*20 = 1920 x 256.
#define TMP_STRIDE 68
#define MAXTAP 17   // worst case: out=16 -> radius 8 -> up to 17 taps
__global__ __launch_bounds__(256) void resize2d_kernel(const float* __restrict__ weight,
                                                       float* __restrict__ ws) {
    int td  = blockIdx.x % 20;
    int row = blockIdx.x / 20;
    int out_h, out_w, oy; float* pe_base;
    if (row < 32)      { out_h = 32; out_w = 32; oy = row;      pe_base = ws + PE32_OFF; }
    else if (row < 48) { out_h = 16; out_w = 16; oy = row - 32; pe_base = ws + PE16_OFF; }
    else               { out_h = 48; out_w = 48; oy = row - 48; pe_base = ws + PE48_OFF; }
    int d0 = td * 64;

    __shared__ float tmp[64 * TMP_STRIDE];
    __shared__ float vcoef[MAXTAP];
    __shared__ int   vmeta[2];                 // i0, n
    __shared__ float hcoef[48][MAXTAP + 1];    // stride 18 floats (bank spread)
    __shared__ int   hj0[48];
    __shared__ int   hn[48];

    int tid = threadIdx.x;

    // Tap tables (1/sum folded in). Vertical: one thread in wave 3;
    // horizontal: one thread per output column (all in wave 0).
    if (tid == 192) {
        int i0, n; float sf, ik, is;
        tap_params(oy, out_h, i0, n, sf, ik, is);
        vmeta[0] = i0; vmeta[1] = n;
        for (int k = 0; k < n; ++k)
            vcoef[k] = keys_cubic((sf - (float)(i0 + k)) * ik) * is;
    }
    if (tid < out_w) {
        int j0, n; float sf, ik, is;
        tap_params(tid, out_w, j0, n, sf, ik, is);
        hj0[tid] = j0; hn[tid] = n;
        for (int k = 0; k < n; ++k)
            hcoef[tid][k] = keys_cubic((sf - (float)(j0 + k)) * ik) * is;
    }
    __syncthreads();

    // Stage 1: vertical (H) resize for this output row into LDS.
    int i0 = vmeta[0], nh = vmeta[1];
    for (int item = tid; item < 1024; item += 256) {
        int x  = item >> 4;        // 0..63 source column
        int f4 = item & 15;        // which float4 of the 64-ch tile
        const float* src = weight + (size_t)x * 1280 + d0 + (f4 << 2);
        float4 acc = make_float4(0.f, 0.f, 0.f, 0.f);
        for (int k = 0; k < nh; ++k) {
            float c = vcoef[k];    // broadcast, conflict-free
            float4 v = *(const float4*)(src + (size_t)(i0 + k) * (64 * 1280));
            acc.x += c * v.x; acc.y += c * v.y; acc.z += c * v.z; acc.w += c * v.w;
        }
        *(float4*)&tmp[x * TMP_STRIDE + (f4 << 2)] = acc;
    }
    __syncthreads();

    // Stage 2: horizontal (W) resize out of LDS, write pe row.
    int nitems = out_w << 4;
    for (int item = tid; item < nitems; item += 256) {
        int ox = item >> 4;
        int f4 = item & 15;
        int j0 = hj0[ox], nw = hn[ox];
        float4 acc = make_float4(0.f, 0.f, 0.f, 0.f);
        for (int k = 0; k < nw; ++k) {
            float c = hcoef[ox][k];
            float4 v = *(const float4*)&tmp[(j0 + k) * TMP_STRIDE + (f4 << 2)];
            acc.x += c * v.x; acc.y += c * v.y; acc.z += c * v.z; acc.w += c * v.w;
        }
        *(float4*)(pe_base + (size_t)(oy * out_w + ox) * 1280 + d0 + (f4 << 2)) = acc;
    }
}

// Wave-per-token streaming add: lane l handles float4s l, l+64, l+128,
// l+192, l+256 of its token (320 f4/token = 5 per lane). Token
// classification is wave-uniform -> zero divergence; 15 independent
// loads issue before any wait (max memory-level parallelism).
// Grid: 25600 tokens / 4 per block = 6400 blocks x 256.
__global__ __launch_bounds__(256) void add_pe_kernel(const float* __restrict__ x,
                                                     const float* __restrict__ weight,
                                                     const float* __restrict__ tw,
                                                     const float* __restrict__ ws,
                                                     float* __restrict__ out) {
    int tid   = threadIdx.x;
    int token = (blockIdx.x << 2) + (tid >> 6);   // 4 tokens per block, 1 per wave
    int off4  = (tid & 63) << 2;                  // this lane's first float offset

    const float* pe;
    int frame;
    if (token < 8192) {            // sample 0: t=8, 32x32
        frame = token >> 10;
        pe = ws + PE32_OFF + (size_t)(token & 1023) * 1280;
    } else if (token < 12288) {    // sample 1: t=16, 16x16
        int l = token - 8192;
        frame = l >> 8;
        pe = ws + PE16_OFF + (size_t)(l & 255) * 1280;
    } else if (token < 21504) {    // sample 2: t=4, 48x48
        int l = token - 12288;
        frame = l / 2304;
        pe = ws + PE48_OFF + (size_t)(l - frame * 2304) * 1280;
    } else {                       // sample 3: t=1, 64x64 -> weight directly, no tw
        frame = -1;
        pe = weight + (size_t)(token - 21504) * 1280;
    }

    size_t base = (size_t)token * 1280 + off4;
    const float* xp = x + base;
    const float* pp = pe + off4;
    float* op = out + base;

    // 5 + 5 independent loads, all in flight before first use.
    f32x4 a0 = __builtin_nontemporal_load((const f32x4*)(xp));
    f32x4 a1 = __builtin_nontemporal_load((const f32x4*)(xp + 256));
    f32x4 a2 = __builtin_nontemporal_load((const f32x4*)(xp + 512));
    f32x4 a3 = __builtin_nontemporal_load((const f32x4*)(xp + 768));
    f32x4 a4 = __builtin_nontemporal_load((const f32x4*)(xp + 1024));
    f32x4 p0 = *(const f32x4*)(pp);
    f32x4 p1 = *(const f32x4*)(pp + 256);
    f32x4 p2 = *(const f32x4*)(pp + 512);
    f32x4 p3 = *(const f32x4*)(pp + 768);
    f32x4 p4 = *(const f32x4*)(pp + 1024);

    a0 += p0; a1 += p1; a2 += p2; a3 += p3; a4 += p4;

    if (frame >= 0) {
        const float* tp = tw + (size_t)frame * 1280 + off4;
        f32x4 t0 = *(const f32x4*)(tp);
        f32x4 t1 = *(const f32x4*)(tp + 256);
        f32x4 t2 = *(const f32x4*)(tp + 512);
        f32x4 t3 = *(const f32x4*)(tp + 768);
        f32x4 t4 = *(const f32x4*)(tp + 1024);
        a0 += t0; a1 += t1; a2 += t2; a3 += t3; a4 += t4;
    }

    __builtin_nontemporal_store(a0, (f32x4*)(op));
    __builtin_nontemporal_store(a1, (f32x4*)(op + 256));
    __builtin_nontemporal_store(a2, (f32x4*)(op + 512));
    __builtin_nontemporal_store(a3, (f32x4*)(op + 768));
    __builtin_nontemporal_store(a4, (f32x4*)(op + 1024));
}

extern "C" void kernel_launch(void* const* d_in, const int* in_sizes, int n_in,
                              void* d_out, int out_size, void* d_ws, size_t ws_size,
                              hipStream_t stream) {
    const float* x      = (const float*)d_in[0];   // [25600,1280]
    const float* weight = (const float*)d_in[1];   // [64,64,1280]
    const float* tw     = (const float*)d_in[2];   // [16,1280]
    // d_in[3] = grid_thws (static metadata, hard-coded)
    float* ws  = (float*)d_ws;
    float* out = (float*)d_out;

    hipLaunchKernelGGL(resize2d_kernel, dim3(1920), dim3(256), 0, stream, weight, ws);
    hipLaunchKernelGGL(add_pe_kernel, dim3(6400), dim3(256), 0, stream, x, weight, tw, ws, out);
}